// Round 9
// baseline (242.603 us; speedup 1.0000x reference)
//
#include <hip/hip_runtime.h>
#include <stdint.h>

#define BATCH    256
#define VOCAB    128000
#define HIST     200
#define TOPK     50
#define CAP      2048
#define NTHREADS 1024
#define BITWORDS (VOCAB / 32)   // 4000 words = 16000 B
#define N4       (VOCAB / 4)    // 32000 float4 per row
#define MAIN4    28672          // 7 iterations x 4096 float4 (asm fast path)

// ----------------------------------------------------------------------------
// Rounds 0-8 evidence: every structure (mono/split/fused, NT/cached stores,
// 1-3 dispatches) lands at ~2.2 TB/s mixed R/W and VGPR_Count=16 — the
// compiler NEVER keeps >1 float4 load in flight, and its load-wait also
// drains the previous iteration's zero-store (same vmcnt FIFO). This round
// forces 4-deep load MLP + store/load decoupling via inline asm:
//   4x global_load_dwordx4 ; 4x global_store_dwordx4(zero) ; s_waitcnt vmcnt(4)
// Loads are oldest -> vmcnt(4) waits loads only, stores stay in flight.
// Entry invariant vmcnt=0 holds (syncthreads after bitmask drains); the
// processing phase issues no global VMEM, so the count is exact.
// ----------------------------------------------------------------------------

typedef float f32x4_t __attribute__((ext_vector_type(4)));

// Monotonic float->uint key: descending float order == descending unsigned order.
__device__ __forceinline__ unsigned fkey_of(float f) {
  unsigned u = __float_as_uint(f);
  return (u & 0x80000000u) ? ~u : (u | 0x80000000u);
}
__device__ __forceinline__ float f_of_key(unsigned k) {
  unsigned u = (k & 0x80000000u) ? (k & 0x7FFFFFFFu) : ~k;
  return __uint_as_float(u);
}
__device__ __forceinline__ float max4v(f32x4_t v) {
  return fmaxf(fmaxf(v[0], v[1]), fmaxf(v[2], v[3]));
}

__global__ __launch_bounds__(NTHREADS) void sample_head_kernel(
    const float* __restrict__ logits, const int* __restrict__ prev,
    float* __restrict__ out)
{
  __shared__ unsigned bitmask[BITWORDS];          // 16000 B
  __shared__ unsigned long long keys[CAP];        // 16384 B
  __shared__ unsigned long long skeys[CAP];       // 16384 B
  __shared__ float evals[CAP];                    //  8192 B
  __shared__ int s_count;
  __shared__ int s_m, s_j;
  __shared__ float s_maxx, s_Z2;

  const int b   = blockIdx.x;
  const int tid = threadIdx.x;
  const float* row  = logits + (size_t)b * VOCAB;
  float*       orow = out    + (size_t)b * VOCAB;

  // ---- seen-token bitmask ----
  for (int i = tid; i < BITWORDS; i += NTHREADS) bitmask[i] = 0u;
  if (tid == 0) s_count = 0;
  __syncthreads();
  for (int i = tid; i < HIST; i += NTHREADS) {
    int t = prev[b * HIST + i];
    atomicOr(&bitmask[t >> 5], 1u << (t & 31));
  }
  __syncthreads();   // also drains all global VMEM -> vmcnt==0 at loop entry

  const f32x4_t* rowx = (const f32x4_t*)row;
  f32x4_t*       outx = (f32x4_t*)orow;

  // T is in pre-temperature (y) space. y ~ N(0,1); kth@50/128000 ~= 3.36 sigma.
  float T = 3.0f;                 // expected count(y>T) ~= 173 in [TOPK, CAP]

  // ---- pass 0: zero row + collect, forced-MLP asm fast path ----
  const f32x4_t z4q = (f32x4_t)0.f;
  for (int it = 0; it < 7; ++it) {
    const int j0 = it * 4096 + tid;           // float4 index of load 0
    const f32x4_t* p0 = rowx + j0;
    const f32x4_t* p1 = p0 + 1024;
    const f32x4_t* p2 = p0 + 2048;
    const f32x4_t* p3 = p0 + 3072;
    f32x4_t* q0 = outx + j0;
    f32x4_t* q1 = q0 + 1024;
    f32x4_t* q2 = q0 + 2048;
    f32x4_t* q3 = q0 + 3072;
    f32x4_t a, bb, c, d;
    asm volatile(
        "global_load_dwordx4 %0, %4, off\n\t"
        "global_load_dwordx4 %1, %5, off\n\t"
        "global_load_dwordx4 %2, %6, off\n\t"
        "global_load_dwordx4 %3, %7, off\n\t"
        "global_store_dwordx4 %8, %12, off\n\t"
        "global_store_dwordx4 %9, %12, off\n\t"
        "global_store_dwordx4 %10, %12, off\n\t"
        "global_store_dwordx4 %11, %12, off\n\t"
        "s_waitcnt vmcnt(4)"
        : "=&v"(a), "=&v"(bb), "=&v"(c), "=&v"(d)
        : "v"(p0), "v"(p1), "v"(p2), "v"(p3),
          "v"(q0), "v"(q1), "v"(q2), "v"(q3), "v"(z4q)
        : "memory");

    // process 4 float4s (indices j0, j0+1024, j0+2048, j0+3072)
    f32x4_t vv[4] = {a, bb, c, d};
    #pragma unroll
    for (int g = 0; g < 4; ++g) {
      const int j = j0 + g * 1024;
      const f32x4_t v = vv[g];
      if (max4v(v) > T) {                     // penalty only lowers y, so raw
        unsigned e0 = 4u * (unsigned)j;       // max <= T => no candidates
        unsigned w  = bitmask[e0 >> 5];
        unsigned sh = e0 & 31;
        #pragma unroll
        for (int l = 0; l < 4; ++l) {
          float vl = v[l];
          float y = vl;
          if ((w >> (sh + l)) & 1u)           // repetition penalty (rare)
            y = (vl < 0.0f) ? vl * 1.2f : vl / 1.2f;
          if (y > T) {
            float x = y / 0.6f;               // temperature (exact IEEE div)
            int pos = atomicAdd(&s_count, 1);
            if (pos < CAP) {
              unsigned k = fkey_of(x);
              keys[pos] = ((unsigned long long)k << 32) |
                          (unsigned)(~(unsigned)(e0 + l));  // smaller idx first
            }
          }
        }
      }
    }
  }
  // ---- tail: remaining 3328 float4, plain path ----
  for (int i = MAIN4 + tid; i < N4; i += NTHREADS) {
    f32x4_t v = rowx[i];
    outx[i] = z4q;
    if (max4v(v) > T) {
      unsigned e0 = 4u * (unsigned)i;
      unsigned w  = bitmask[e0 >> 5];
      unsigned sh = e0 & 31;
      #pragma unroll
      for (int l = 0; l < 4; ++l) {
        float vl = v[l];
        float y = vl;
        if ((w >> (sh + l)) & 1u)
          y = (vl < 0.0f) ? vl * 1.2f : vl / 1.2f;
        if (y > T) {
          float x = y / 0.6f;
          int pos = atomicAdd(&s_count, 1);
          if (pos < CAP) {
            unsigned k = fkey_of(x);
            keys[pos] = ((unsigned long long)k << 32) |
                        (unsigned)(~(unsigned)(e0 + l));
          }
        }
      }
    }
  }
  asm volatile("s_waitcnt vmcnt(0)" ::: "memory");  // drain zero-stores
  __syncthreads();
  int cnt = s_count;

  // ---- retry passes (bisection safety net; never taken for this input) ----
  if (cnt < TOPK || cnt > CAP) {
    float Tlo = 0.f, Thi = 0.f;
    bool hasLo = false, hasHi = false;
    for (int attempt = 0; attempt < 40; ++attempt) {
      if (cnt < TOPK) { Thi = T; hasHi = true; T = hasLo ? 0.5f * (T + Tlo) : T - 1.0f; }
      else            { Tlo = T; hasLo = true; T = hasHi ? 0.5f * (T + Thi) : T + 1.0f; }
      __syncthreads();
      if (tid == 0) s_count = 0;
      __syncthreads();
      for (int i = tid; i < N4; i += NTHREADS) {
        f32x4_t v4 = rowx[i];
        int v0 = i * 4;
        unsigned w  = bitmask[v0 >> 5];
        unsigned sh = v0 & 31;
        #pragma unroll
        for (int l = 0; l < 4; ++l) {
          float v = v4[l];
          float y = v;
          if ((w >> (sh + l)) & 1u)
            y = (v < 0.0f) ? v * 1.2f : v / 1.2f;
          if (y > T) {
            float x = y / 0.6f;
            int pos = atomicAdd(&s_count, 1);
            if (pos < CAP) {
              unsigned k = fkey_of(x);
              keys[pos] = ((unsigned long long)k << 32) |
                          (unsigned)(~(unsigned)(v0 + l));
            }
          }
        }
      }
      __syncthreads();
      cnt = s_count;
      if (cnt >= TOPK && cnt <= CAP) break;
    }
    if (cnt > CAP) cnt = CAP;   // pathological-tie fallback (never for this input)
  }

  // ---- rank sort: keys unique (idx tie-break) => ranks are a bijection.
  // 2 barriers total vs bitonic's ~36 (each barrier drains the write queue).
  for (int i = tid; i < cnt; i += NTHREADS) {
    unsigned long long a = keys[i];
    int r = 0;
    for (int j = 0; j < cnt; ++j) r += (keys[j] > a);
    skeys[r] = a;
  }
  __syncthreads();

  // ---- top-k boundary (keep ties at kth) + max ----
  if (tid == 0) {
    int kk = (cnt < TOPK) ? cnt : TOPK;
    unsigned kth = (unsigned)(skeys[kk - 1] >> 32);
    int m = kk;
    while (m < cnt && (unsigned)(skeys[m] >> 32) == kth) m++;
    s_m = m;
    s_maxx = f_of_key((unsigned)(skeys[0] >> 32));
  }
  __syncthreads();
  int m = s_m;
  float maxx = s_maxx;
  for (int i = tid; i < m; i += NTHREADS)
    evals[i] = expf(f_of_key((unsigned)(skeys[i] >> 32)) - maxx);
  __syncthreads();

  // ---- nucleus cutoff: keep token i iff i==0 or cumsum(p[0..i-1]) <= 0.9 ----
  if (tid == 0) {
    float Z = 0.f;
    for (int i = 0; i < m; ++i) Z += evals[i];
    float cum = 0.f;
    int j = 0;
    for (int i = 0; i < m; ++i) {
      if (i > 0 && cum > 0.9f) break;
      cum += evals[i] / Z;
      j = i + 1;
    }
    float Z2 = 0.f;
    for (int i = 0; i < j; ++i) Z2 += evals[i];
    s_j = j; s_Z2 = Z2;
  }
  __syncthreads();

  // ---- scatter final probs (row zeroed in pass 0; drains above guarantee
  // ordering vs the zero-stores) ----
  int j = s_j;
  float Z2 = s_Z2;
  for (int i = tid; i < j; i += NTHREADS) {
    int idx = (int)(~(unsigned)(skeys[i] & 0xFFFFFFFFull));
    orow[idx] = evals[i] / Z2;
  }
}

extern "C" void kernel_launch(void* const* d_in, const int* in_sizes, int n_in,
                              void* d_out, int out_size, void* d_ws, size_t ws_size,
                              hipStream_t stream) {
  const float* logits = (const float*)d_in[0];
  const int*   prev   = (const int*)d_in[1];
  float*       out    = (float*)d_out;
  hipLaunchKernelGGL(sample_head_kernel, dim3(BATCH), dim3(NTHREADS), 0, stream,
                     logits, prev, out);
}